// Round 1
// baseline (348.581 us; speedup 1.0000x reference)
//
#include <hip/hip_runtime.h>

// LSTM decoder: B=1024, S=256, H=128, O=7, T=512
// gates = h @ (W_ih+W_hh).T + (b_ih+b_hh)   (reference uses h for BOTH matmuls)
// c' = sig(f)*c + sig(i)*tanh(g); h' = sig(o)*tanh(c'); pred = h' @ W_out.T + b_out
//
// 256 blocks x 512 threads, 4 batch rows/block, persistent over all 512 steps.
// W in VGPRs (bf16), h in double-buffered LDS (bf16, swizzled), c in VGPRs.
// One __syncthreads per step. pred fused as extra MFMA N-tile on wave 0.

#define RB   4      // batch rows per block
#define HH   128
#define SSEQ 256
#define TT   512
#define OO   7

typedef __attribute__((ext_vector_type(8))) short short8;
typedef __attribute__((ext_vector_type(4))) float f32x4;

__device__ __forceinline__ unsigned short f2bf(float x) {
    union { float f; unsigned u; } v; v.f = x;
    return (unsigned short)((v.u + 0x7FFF + ((v.u >> 16) & 1)) >> 16); // RNE
}

__device__ __forceinline__ float sigmoidf_(float x) {
    return __builtin_amdgcn_rcpf(1.f + __expf(-x));
}
__device__ __forceinline__ float tanhf_(float x) {
    return 1.f - 2.f * __builtin_amdgcn_rcpf(__expf(2.f * x) + 1.f);
}

__global__ __launch_bounds__(512, 2)
void lstm_decoder_kernel(const float* __restrict__ ctx,
                         const float* __restrict__ Wih,
                         const float* __restrict__ Whh,
                         const float* __restrict__ bih,
                         const float* __restrict__ bhh,
                         const float* __restrict__ Wout,
                         const float* __restrict__ bout,
                         float* __restrict__ out) {
    // h state: bf16, double buffered, swizzled: short idx = (row*128+k) ^ (row<<3)
    __shared__ __align__(16) unsigned short h_lds[2][RB * HH];
    // wave-private gate scratch: [wave][g*64 + row*16 + col]
    __shared__ float gsc[8][256];

    const int tid  = threadIdx.x;
    const int lane = tid & 63;
    const int wave = tid >> 6;
    const int rowBase = blockIdx.x * RB;

    // elementwise coords: each lane owns (erow, ej); wave w owns j in [16w,16w+16)
    const int erow = lane >> 4;                 // 0..3
    const int ej   = wave * 16 + (lane & 15);   // 0..127

    // folded biases (i,f,g,o) for this lane's gate column
    const float bi  = bih[ej]          + bhh[ej];
    const float bf_ = bih[HH + ej]     + bhh[HH + ej];
    const float bg  = bih[2 * HH + ej] + bhh[2 * HH + ej];
    const float bo  = bih[3 * HH + ej] + bhh[3 * HH + ej];

    // W fragments in registers: wave w, gate g -> N-tile nt = g*8 + w
    // B-frag: lane holds W[n][k0..k0+7], n = nt*16 + (lane&15), k0 = kt*32 + (lane>>4)*8
    short8 wfrag[4][4];
#pragma unroll
    for (int g = 0; g < 4; ++g) {
        const int n = g * 128 + wave * 16 + (lane & 15);
#pragma unroll
        for (int kt = 0; kt < 4; ++kt) {
            const int k0 = kt * 32 + ((lane >> 4) << 3);
            const float* p1 = Wih + (size_t)n * HH + k0;
            const float* p2 = Whh + (size_t)n * HH + k0;
            short8 w;
#pragma unroll
            for (int j = 0; j < 8; ++j) w[j] = (short)f2bf(p1[j] + p2[j]);
            wfrag[g][kt] = w;
        }
    }

    // pred tile (W_out, cols 0..6, zero-padded to 16) on wave 0
    short8 wpred[4];
    float bo_pred = 0.f;
    if (wave == 0) {
        const int col = lane & 15;
#pragma unroll
        for (int kt = 0; kt < 4; ++kt) {
            const int k0 = kt * 32 + ((lane >> 4) << 3);
            short8 w;
#pragma unroll
            for (int j = 0; j < 8; ++j)
                w[j] = (col < OO) ? (short)f2bf(Wout[(size_t)col * HH + k0 + j]) : (short)0;
            wpred[kt] = w;
        }
        if (col < OO) bo_pred = bout[col];
    }

    // h0 = context_seq[:, S-1, :]
    {
        const float v = ctx[(size_t)(rowBase + erow) * SSEQ * HH + (size_t)(SSEQ - 1) * HH + ej];
        h_lds[0][(erow * 128 + ej) ^ (erow << 3)] = f2bf(v);
    }
    float c_st = 0.f;   // cell state for (erow, ej)
    __syncthreads();

    const int ar  = lane & 15;   // MFMA A row 0..15
    const int arw = ar & 3;      // wrapped to real rows 0..3 (rows 4..15 are duplicates, outputs unused)

    for (int it = 0; it <= TT; ++it) {
        const int cur = it & 1;

        // A fragments: lane holds h[arw][k0..k0+7]
        short8 afrag[4];
#pragma unroll
        for (int kt = 0; kt < 4; ++kt) {
            const int k0 = kt * 32 + ((lane >> 4) << 3);
            const int si = (arw * 128 + k0) ^ (arw << 3);
            afrag[kt] = *(const short8*)&h_lds[cur][si];
        }

        // gate MFMAs: 4 gate tiles x 4 K-tiles
        f32x4 acc0 = {0.f, 0.f, 0.f, 0.f};
        f32x4 acc1 = {0.f, 0.f, 0.f, 0.f};
        f32x4 acc2 = {0.f, 0.f, 0.f, 0.f};
        f32x4 acc3 = {0.f, 0.f, 0.f, 0.f};
#pragma unroll
        for (int kt = 0; kt < 4; ++kt) {
            acc0 = __builtin_amdgcn_mfma_f32_16x16x32_bf16(afrag[kt], wfrag[0][kt], acc0, 0, 0, 0);
            acc1 = __builtin_amdgcn_mfma_f32_16x16x32_bf16(afrag[kt], wfrag[1][kt], acc1, 0, 0, 0);
            acc2 = __builtin_amdgcn_mfma_f32_16x16x32_bf16(afrag[kt], wfrag[2][kt], acc2, 0, 0, 0);
            ac3:;
            acc3 = __builtin_amdgcn_mfma_f32_16x16x32_bf16(afrag[kt], wfrag[3][kt], acc3, 0, 0, 0);
        }

        // pred = h_it @ Wout.T  (h_it = h_{t+1} of iteration it-1 -> output step it-1)
        if (wave == 0) {
            f32x4 accp = {0.f, 0.f, 0.f, 0.f};
#pragma unroll
            for (int kt = 0; kt < 4; ++kt)
                accp = __builtin_amdgcn_mfma_f32_16x16x32_bf16(afrag[kt], wpred[kt], accp, 0, 0, 0);
            if (it > 0 && (lane >> 4) == 0 && (lane & 15) < OO) {
                const int col = lane & 15;
#pragma unroll
                for (int r = 0; r < 4; ++r)
                    out[(size_t)(rowBase + r) * TT * OO + (size_t)(it - 1) * OO + col] =
                        accp[r] + bo_pred;
            }
        }

        if (it == TT) break;

        // redistribute gates: C/D layout row=(lane>>4)*4+reg -> valid rows live in
        // lanes 0..15 regs 0..3. Spread to all 64 lanes via wave-private LDS
        // (same-wave DS ops are in-order: no barrier).
        if ((lane >> 4) == 0) {
            float* gw = &gsc[wave][lane & 15];
#pragma unroll
            for (int r = 0; r < 4; ++r) {
                gw[0 * 64 + r * 16] = acc0[r];
                gw[1 * 64 + r * 16] = acc1[r];
                gw[2 * 64 + r * 16] = acc2[r];
                gw[3 * 64 + r * 16] = acc3[r];
            }
        }
        const float* gr = &gsc[wave][(lane >> 4) * 16 + (lane & 15)];
        const float gi = gr[0]   + bi;
        const float gf = gr[64]  + bf_;
        const float gg = gr[128] + bg;
        const float go = gr[192] + bo;

        const float si_ = sigmoidf_(gi);
        const float sf_ = sigmoidf_(gf);
        const float so_ = sigmoidf_(go);
        const float tg  = tanhf_(gg);
        c_st = sf_ * c_st + si_ * tg;
        const float hnew = so_ * tanhf_(c_st);

        h_lds[cur ^ 1][(erow * 128 + ej) ^ (erow << 3)] = f2bf(hnew);
        __syncthreads();
    }
}

extern "C" void kernel_launch(void* const* d_in, const int* in_sizes, int n_in,
                              void* d_out, int out_size, void* d_ws, size_t ws_size,
                              hipStream_t stream) {
    const float* ctx  = (const float*)d_in[0];
    const float* Wih  = (const float*)d_in[1];
    const float* Whh  = (const float*)d_in[2];
    const float* bih  = (const float*)d_in[3];
    const float* bhh  = (const float*)d_in[4];
    const float* Wout = (const float*)d_in[5];
    const float* bout = (const float*)d_in[6];
    float* out = (float*)d_out;

    lstm_decoder_kernel<<<dim3(1024 / RB), dim3(512), 0, stream>>>(
        ctx, Wih, Whh, bih, bhh, Wout, bout, out);
}